// Round 7
// baseline (341.571 us; speedup 1.0000x reference)
//
#include <hip/hip_runtime.h>

#define D 64
#define EPS 0.006f
#define KSPLIT 2

typedef __attribute__((ext_vector_type(8))) short bf16x8;
typedef __attribute__((ext_vector_type(4))) float f32x4;

// RNE fp32 -> bf16 (bit trick; matches HW cvt for normal values)
static __device__ __forceinline__ short f2bf(float x) {
    unsigned u = __float_as_uint(x);
    unsigned r = u + 0x7fff + ((u >> 16) & 1);
    return (short)(r >> 16);
}
static __device__ __forceinline__ float bf2f(short s) {
    return __uint_as_float(((unsigned)(unsigned short)s) << 16);
}

// Fused: centroid fp32 -> (hi,lo) bf16 split + c2 row norms + counter zero.
// c2 summation order identical to round-6 c2_kernel (keeps exact-path stable).
__global__ void prep_kernel(const float* __restrict__ c, short* __restrict__ ch,
                            short* __restrict__ cl, float* __restrict__ c2,
                            int K, int* __restrict__ counter) {
    int t = blockIdx.x * blockDim.x + threadIdx.x;
    if (t == 0) *counter = 0;
    const int nf4 = K * (D / 4);
    if (t < nf4) {
        float4 v = ((const float4*)c)[t];
        short hx = f2bf(v.x), hy = f2bf(v.y), hz = f2bf(v.z), hw = f2bf(v.w);
        ((short4*)ch)[t] = make_short4(hx, hy, hz, hw);
        ((short4*)cl)[t] = make_short4(f2bf(v.x - bf2f(hx)), f2bf(v.y - bf2f(hy)),
                                       f2bf(v.z - bf2f(hz)), f2bf(v.w - bf2f(hw)));
    }
    if (t < K) {
        const float4* cp = (const float4*)(c + (size_t)t * D);
        float s = 0.f;
#pragma unroll
        for (int i = 0; i < D / 4; ++i) {
            float4 v = cp[i];
            s += v.x * v.x; s += v.y * v.y; s += v.z * v.z; s += v.w * v.w;
        }
        c2[t] = s;
    }
}

// Pass 1: split-bf16 MFMA distance scan, top-2 tracking, K split over
// blockIdx.y. Register double-buffer on B loads.
// score(n,k) = c2[k] - 2*dot(a,c); dot ~= ah.ch + ah.cl + al.ch
// __launch_bounds__(256,4): VGPR cap 128 so ah/al+prefetch+top2 state stay in
// VGPRs (round-6's 56-reg allocation forced AGPR shuffling -> VALU bloat).
__global__ __launch_bounds__(256, 4) void pass1_kernel(
    const float* __restrict__ action, const short* __restrict__ ch,
    const short* __restrict__ cl, const float* __restrict__ c2,
    float4* __restrict__ cand, int N, int K) {
    const int tid  = threadIdx.x;
    const int wv   = tid >> 6;
    const int lane = tid & 63;
    const int col  = lane & 15;
    const int quad = lane >> 4;
    const int m0   = blockIdx.x * 128 + wv * 32;
    const int KC   = K / KSPLIT;
    const int k0   = blockIdx.y * KC;
    const int k1   = k0 + KC;

    // A fragments: fp32 -> (hi, lo) bf16 in registers, once.
    bf16x8 ah[2][2], al[2][2];
#pragma unroll
    for (int mi = 0; mi < 2; ++mi) {
        const float* arow = action + (size_t)(m0 + mi * 16 + col) * D;
#pragma unroll
        for (int ks = 0; ks < 2; ++ks) {
            const float* src = arow + ks * 32 + quad * 8;
            bf16x8 h, l;
#pragma unroll
            for (int j = 0; j < 8; ++j) {
                float x = src[j];
                short hs = f2bf(x);
                h[j] = hs;
                l[j] = f2bf(x - bf2f(hs));
            }
            ah[mi][ks] = h;
            al[mi][ks] = l;
        }
    }

    float b1[8], b2[8];
    int   bk[8];
#pragma unroll
    for (int e = 0; e < 8; ++e) {
        b1[e] = __builtin_inff(); b2[e] = __builtin_inff(); bk[e] = k0;
    }

    // prologue prefetch (iter 0)
    bf16x8 pbh0, pbh1, pbl0, pbl1;
    float  pcc;
    {
        const size_t kb = (size_t)(k0 + col) * D + quad * 8;
        pbh0 = *(const bf16x8*)(ch + kb);
        pbh1 = *(const bf16x8*)(ch + kb + 32);
        pbl0 = *(const bf16x8*)(cl + kb);
        pbl1 = *(const bf16x8*)(cl + kb + 32);
        pcc  = c2[k0 + col];
    }

#pragma unroll 2
    for (int n0 = k0; n0 < k1; n0 += 16) {
        bf16x8 bh0 = pbh0, bh1 = pbh1, bl0 = pbl0, bl1 = pbl1;
        const float cc = pcc;
        const int   k  = n0 + col;

        // prefetch next iteration (hides L2 latency under MFMA+fold)
        const int np = n0 + 16;
        if (np < k1) {
            const size_t kb = (size_t)(np + col) * D + quad * 8;
            pbh0 = *(const bf16x8*)(ch + kb);
            pbh1 = *(const bf16x8*)(ch + kb + 32);
            pbl0 = *(const bf16x8*)(cl + kb);
            pbl1 = *(const bf16x8*)(cl + kb + 32);
            pcc  = c2[np + col];
        }

#pragma unroll
        for (int mi = 0; mi < 2; ++mi) {
            f32x4 acc = {0.f, 0.f, 0.f, 0.f};
            acc = __builtin_amdgcn_mfma_f32_16x16x32_bf16(al[mi][0], bh0, acc, 0, 0, 0);
            acc = __builtin_amdgcn_mfma_f32_16x16x32_bf16(ah[mi][0], bl0, acc, 0, 0, 0);
            acc = __builtin_amdgcn_mfma_f32_16x16x32_bf16(ah[mi][0], bh0, acc, 0, 0, 0);
            acc = __builtin_amdgcn_mfma_f32_16x16x32_bf16(al[mi][1], bh1, acc, 0, 0, 0);
            acc = __builtin_amdgcn_mfma_f32_16x16x32_bf16(ah[mi][1], bl1, acc, 0, 0, 0);
            acc = __builtin_amdgcn_mfma_f32_16x16x32_bf16(ah[mi][1], bh1, acc, 0, 0, 0);
#pragma unroll
            for (int r = 0; r < 4; ++r) {
                const int e = mi * 4 + r;
                const float s = fmaf(-2.f, acc[r], cc);
                const float mid = fmaxf(s, b1[e]);     // loser of (s, b1)
                b2[e] = fminf(b2[e], mid);
                const bool better = s < b1[e];          // strict <: first-min
                b1[e] = fminf(b1[e], s);
                bk[e] = better ? k : bk[e];
            }
        }
    }

    // cross-lane top-2 merge over the 16 centroid columns
#pragma unroll
    for (int off = 1; off < 16; off <<= 1) {
#pragma unroll
        for (int e = 0; e < 8; ++e) {
            float o1 = __shfl_xor(b1[e], off, 64);
            float o2 = __shfl_xor(b2[e], off, 64);
            int   ok = __shfl_xor(bk[e], off, 64);
            bool take = (o1 < b1[e]) || (o1 == b1[e] && ok < bk[e]);
            float nb2 = take ? fminf(b1[e], o2) : fminf(b2[e], o1);
            b1[e] = take ? o1 : b1[e];
            bk[e] = take ? ok : bk[e];
            b2[e] = nb2;
        }
    }

    if (col == 0) {
#pragma unroll
        for (int e = 0; e < 8; ++e) {
            const int mi = e >> 2, r = e & 3;
            const int p = m0 + mi * 16 + quad * 4 + r;
            cand[(size_t)blockIdx.y * N + p] =
                make_float4(b1[e], b2[e], (float)bk[e], 0.f);
        }
    }
}

// Fused merge + bin write + ambiguity flag + exact fp32 residual.
// Split0 owns lower k, so >= keeps split0 on ties = numpy first-min.
__global__ __launch_bounds__(256) void resflag_kernel(
    const float* __restrict__ action, const float* __restrict__ centroids,
    const float4* __restrict__ cand, float* __restrict__ out_bin,
    float* __restrict__ out_res, int* __restrict__ counter,
    int* __restrict__ flags, int N) {
    int n = blockIdx.x * blockDim.x + threadIdx.x;
    if (n >= N) return;
    float4 v0 = cand[n];
    float4 v1 = cand[(size_t)N + n];
    float b1, b2; int bk;
    if (v1.x < v0.x) { b1 = v1.x; bk = (int)v1.z; b2 = fminf(v0.x, v1.y); }
    else             { b1 = v0.x; bk = (int)v0.z; b2 = fminf(v1.x, v0.y); }
    out_bin[n] = (float)bk;
    if (b2 - b1 < EPS) {
        int idx = atomicAdd(counter, 1);
        flags[idx] = n;
    }
    const float4* ap = (const float4*)(action + (size_t)n * D);
    const float4* cp = (const float4*)(centroids + (size_t)bk * D);
    float4*       rp = (float4*)(out_res + (size_t)n * D);
#pragma unroll
    for (int i = 0; i < D / 4; ++i) {
        float4 a = ap[i], c = cp[i];
        rp[i] = make_float4(a.x - c.x, a.y - c.y, a.z - c.z, a.w - c.w);
    }
}

// Exact fp32 rescan, point-tiled: 32 flagged points per block, centroids
// staged through LDS in 64-row chunks (32x less L2 traffic than per-point
// streaming). Thread t: point p=t&31, centroid slice kk=t>>5 (8 rows/chunk).
// Ascending k per thread + lexicographic (score,k) merge = numpy first-min.
__global__ __launch_bounds__(256) void exact_kernel(
    const float* __restrict__ action, const float* __restrict__ centroids,
    const float* __restrict__ c2, const int* __restrict__ counter,
    const int* __restrict__ flags, float* __restrict__ out_bin,
    float* __restrict__ out_res, int K) {
    __shared__ float4 As[32 * (D / 4)];     // 8 KB
    __shared__ float4 Cs[64 * (D / 4)];     // 16 KB
    __shared__ float  rv[256];
    __shared__ int    rk[256];
    __shared__ int    s_bk[32];
    const int count = *counter;
    const int tid = threadIdx.x;
    const int base = blockIdx.x * 32;
    if (base >= count) return;
    const int p  = tid & 31;
    const int kk = tid >> 5;

    // stage the 32 action rows (invalid tail rows left as garbage; guarded on
    // output). 512 float4s, 2 per thread.
#pragma unroll
    for (int j = 0; j < 2; ++j) {
        int idx = tid + j * 256;                 // row = idx/16, f4col = idx%16
        int gi  = base + (idx >> 4);
        if (gi < count) {
            int n = flags[gi];
            As[idx] = ((const float4*)(action + (size_t)n * D))[idx & 15];
        }
    }

    float best = __builtin_inff();
    int   bbk  = 0x7fffffff;

    for (int kt = 0; kt < K; kt += 64) {
        __syncthreads();
        // stage 64 centroid rows: 1024 float4s, 4 per thread
#pragma unroll
        for (int j = 0; j < 4; ++j) {
            int idx = tid + j * 256;
            Cs[idx] = ((const float4*)(centroids + (size_t)kt * D))[idx];
        }
        __syncthreads();
#pragma unroll
        for (int ci = 0; ci < 8; ++ci) {
            const int kr = kk * 8 + ci;
            const int k  = kt + kr;
            const float4* ar = &As[p * (D / 4)];
            const float4* cr = &Cs[kr * (D / 4)];
            float dot = 0.f;
#pragma unroll
            for (int d = 0; d < D / 4; ++d) {
                float4 a = ar[d], c = cr[d];
                dot = fmaf(a.x, c.x, dot); dot = fmaf(a.y, c.y, dot);
                dot = fmaf(a.z, c.z, dot); dot = fmaf(a.w, c.w, dot);
            }
            float s = fmaf(-2.f, dot, c2[k]);
            if (s < best) { best = s; bbk = k; }   // ascending k: first-min
        }
    }

    rv[tid] = best; rk[tid] = bbk;
    __syncthreads();
    if (tid < 32) {
        float bb = rv[tid]; int bki = rk[tid];
#pragma unroll
        for (int j = 1; j < 8; ++j) {
            float v = rv[j * 32 + tid]; int kx = rk[j * 32 + tid];
            if (v < bb || (v == bb && kx < bki)) { bb = v; bki = kx; }
        }
        s_bk[tid] = bki;
        int gi = base + tid;
        if (gi < count) out_bin[flags[gi]] = (float)bki;
    }
    __syncthreads();
    // parallel residual: 8 threads per point write 2 float4s each
    {
        int gi = base + p;
        if (gi < count) {
            int n  = flags[gi];
            int bi = s_bk[p];
#pragma unroll
            for (int j = 0; j < 2; ++j) {
                int d4 = kk * 2 + j;
                float4 a = As[p * (D / 4) + d4];
                float4 c = ((const float4*)(centroids + (size_t)bi * D))[d4];
                ((float4*)(out_res + (size_t)n * D))[d4] =
                    make_float4(a.x - c.x, a.y - c.y, a.z - c.z, a.w - c.w);
            }
        }
    }
}

extern "C" void kernel_launch(void* const* d_in, const int* in_sizes, int n_in,
                              void* d_out, int out_size, void* d_ws, size_t ws_size,
                              hipStream_t stream) {
    const float* action    = (const float*)d_in[0];  // [N, 64]
    const float* centroids = (const float*)d_in[1];  // [K, 64]
    const int N = in_sizes[0] / D;  // 65536
    const int K = in_sizes[1] / D;  // 2048

    float* out_bin = (float*)d_out;      // N floats: argmin index
    float* out_res = (float*)d_out + N;  // N*D residuals

    // ws layout (~2.9 MB)
    char* w = (char*)d_ws;
    float*  c2      = (float*)w;                       // 8 KB
    int*    counter = (int*)(w + 8192);                // 4 B (padded to 256)
    int*    flags   = (int*)(w + 8448);                // N*4 = 256 KB
    short*  ch      = (short*)(w + 8448 + 262144);     // K*D*2 = 256 KB
    short*  cl      = ch + (size_t)K * D;              // 256 KB
    float4* cand    = (float4*)(cl + (size_t)K * D);   // KSPLIT*N*16 = 2 MB

    prep_kernel<<<(K * (D / 4) + 255) / 256, 256, 0, stream>>>(centroids, ch, cl,
                                                               c2, K, counter);
    dim3 g1(N / 128, KSPLIT);
    pass1_kernel<<<g1, 256, 0, stream>>>(action, ch, cl, c2, cand, N, K);
    resflag_kernel<<<(N + 255) / 256, 256, 0, stream>>>(action, centroids, cand,
                                                        out_bin, out_res, counter,
                                                        flags, N);
    exact_kernel<<<2048, 256, 0, stream>>>(action, centroids, c2, counter, flags,
                                           out_bin, out_res, K);
}